// Round 13
// baseline (278.105 us; speedup 1.0000x reference)
//
#include <hip/hip_runtime.h>
#include <math.h>

// 256-point FFT = 16x16 four-step Cooley-Tukey, one batch per 16 lanes,
// ZERO LDS: the mid transpose is done in registers via 4 shfl_xor
// butterfly stages (masks 1,2,4,8 -- recursive 2x2 block transpose, all
// register indices compile-time). Removing the 17.4KB LDS tile lifts the
// blocks/CU cap and removes the 4 fenced LDS phases that serialized each
// wave, so many more staggered waves keep loads in flight (rounds 8-12
// diagnosis: latency-bound at 4.2/6.3 TB/s, no pipe saturated).
// Cache policy (round 8): PLAIN loads (input ~50% L3-resident across
// replays) + NT stores (write-once output). State ~52 VGPR -> fits the
// 64-VGPR/8-wave tier naturally; no launch-bounds forcing (rounds 4/5/9
// lesson: forcing a tier the state can't fit = spills).

__device__ __forceinline__ void fft16(float re[16], float im[16]) {
    // 4-bit bit-reversal permutation (swap i < rev(i))
    {
        float tr, ti;
#define SWP(a, b) tr = re[a]; re[a] = re[b]; re[b] = tr; ti = im[a]; im[a] = im[b]; im[b] = ti;
        SWP(1, 8) SWP(2, 4) SWP(3, 12) SWP(5, 10) SWP(7, 14) SWP(11, 13)
#undef SWP
    }
    const float C[8] = { 1.0f,  0.92387953251f,  0.70710678119f,  0.38268343236f,
                         0.0f, -0.38268343236f, -0.70710678119f, -0.92387953251f };
    const float S16[8] = { 0.0f, -0.38268343236f, -0.70710678119f, -0.92387953251f,
                          -1.0f, -0.92387953251f, -0.70710678119f, -0.38268343236f };
#pragma unroll
    for (int s = 1; s <= 4; ++s) {
        const int len = 1 << s;
        const int half = len >> 1;
        const int step = 16 >> s;
#pragma unroll
        for (int i = 0; i < 16; i += len) {
#pragma unroll
            for (int j = 0; j < half; ++j) {
                const float wr = C[j * step];
                const float wi = S16[j * step];
                const int p = i + j;
                const int q = i + j + half;
                const float vr = re[q] * wr - im[q] * wi;
                const float vi = re[q] * wi + im[q] * wr;
                const float ur = re[p], ui = im[p];
                re[p] = ur + vr; im[p] = ui + vi;
                re[q] = ur - vr; im[q] = ui - vi;
            }
        }
    }
}

// 16x16 transpose across the 16 lanes of a quarter-wave via shfl_xor
// butterflies. Lane t holds row t (elements k=0..15); after, lane t holds
// column t. Masks 1,2,4,8 only touch lane-id bits 0..3, so the exchange
// stays inside each 16-lane group of the 64-lane wave. All register
// indices are compile-time (rule #20 safe).
__device__ __forceinline__ void xpose16(float re[16], float im[16], int t) {
#pragma unroll
    for (int m = 1; m <= 8; m <<= 1) {
        const bool hi = (t & m) != 0;
#pragma unroll
        for (int k = 0; k < 16; ++k) {
            if ((k & m) == 0) {
                const int kp = k | m;
                float vr = hi ? re[k] : re[kp];
                float vi = hi ? im[k] : im[kp];
                vr = __shfl_xor(vr, m, 64);
                vi = __shfl_xor(vi, m, 64);
                if (hi) { re[k] = vr; im[k] = vi; }
                else    { re[kp] = vr; im[kp] = vi; }
            }
        }
    }
}

__global__ __launch_bounds__(256) void fft256_kernel(const float* __restrict__ x,
                                                     float* __restrict__ out) {
    const int tid = threadIdx.x;
    const int t   = tid & 15;
    const long b  = (long)blockIdx.x * 16 + (tid >> 4);

    const float* xr = x + b * 512;   // x[b, 0, :]
    const float* xi = xr + 256;      // x[b, 1, :]

    float re[16], im[16];

    // Plain loads: input stays L3-resident across timed replays
    // (round 8: FETCH 230->131MB vs nt loads). 64B segments, coalesced.
#pragma unroll
    for (int i = 0; i < 16; ++i) re[i] = xr[t + 16 * i];
#pragma unroll
    for (int i = 0; i < 16; ++i) im[i] = xi[t + 16 * i];

    fft16(re, im);  // Y[t, k2] over n2

    // Twiddle W_256^{t*k}, fully in registers.
#pragma unroll
    for (int k = 0; k < 16; ++k) {
        float sv, cv;
        __sincosf(-6.283185307179586f * (float)(t * k) * (1.0f / 256.0f), &sv, &cv);
        const float tr = re[k] * cv - im[k] * sv;
        const float ti = re[k] * sv + im[k] * cv;
        re[k] = tr;
        im[k] = ti;
    }

    xpose16(re, im, t);  // lane t now holds Z[n][t], n=0..15

    fft16(re, im);  // X[t + 16*k1] over k1

    // NT stores: write-once output, evict-first; 64B segments coalesced.
    float* outr = out + b * 512;
    float* outi = outr + 256;
#pragma unroll
    for (int k = 0; k < 16; ++k) __builtin_nontemporal_store(re[k], outr + t + 16 * k);
#pragma unroll
    for (int k = 0; k < 16; ++k) __builtin_nontemporal_store(im[k], outi + t + 16 * k);
}

extern "C" void kernel_launch(void* const* d_in, const int* in_sizes, int n_in,
                              void* d_out, int out_size, void* d_ws, size_t ws_size,
                              hipStream_t stream) {
    (void)d_ws; (void)ws_size; (void)n_in; (void)out_size;
    const float* x = (const float*)d_in[0];
    float* out = (float*)d_out;
    const int batches = in_sizes[0] / 512;   // 131072
    const int grid = batches / 16;           // 8192 blocks
    fft256_kernel<<<grid, 256, 0, stream>>>(x, out);
}

// Round 14
// 99.690 us; speedup vs baseline: 2.7897x; 2.7897x over previous
//
#include <hip/hip_runtime.h>
#include <math.h>

// 256-point FFT = 16x16 four-step Cooley-Tukey, one batch per 16 lanes,
// FOUR batches per thread processed SEQUENTIALLY (grid-stride style):
// same 32 data VGPRs reused each iteration (no pressure growth -- the
// allocator refuses >64-VGPR live state, proven rounds 9-11), LDS tile
// reused, wave launch + final store-drain amortized 4x. sched_barrier(0)
// between iterations stops the scheduler from cross-iteration pipelining
// (which would blow registers, round 9/13 lesson).
// Cache policy (round 8): PLAIN loads (input ~50% L3-resident across
// replays, FETCH 230->131MB) + NT stores (write-once output, clean
// WRITE 273MB). Single wave-private 16x17 LDS tile per sub, reused
// re-then-im -> 17.4 KB/block. No __syncthreads (wave-private LDS,
// in-order per-wave DS ops). No shfl: DS-pipe shuffles cost 70M bank
// conflicts + spills (round 13).

#define NB  16   // batches in flight per 256-thread block
#define TS  272  // 16*17 floats per-batch tile
#define BPT 4    // sequential batches per thread

__device__ __forceinline__ void wave_fence() {
    __builtin_amdgcn_wave_barrier();
}

__device__ __forceinline__ void fft16(float re[16], float im[16]) {
    // 4-bit bit-reversal permutation (swap i < rev(i))
    {
        float tr, ti;
#define SWP(a, b) tr = re[a]; re[a] = re[b]; re[b] = tr; ti = im[a]; im[a] = im[b]; im[b] = ti;
        SWP(1, 8) SWP(2, 4) SWP(3, 12) SWP(5, 10) SWP(7, 14) SWP(11, 13)
#undef SWP
    }
    const float C[8] = { 1.0f,  0.92387953251f,  0.70710678119f,  0.38268343236f,
                         0.0f, -0.38268343236f, -0.70710678119f, -0.92387953251f };
    const float S16[8] = { 0.0f, -0.38268343236f, -0.70710678119f, -0.92387953251f,
                          -1.0f, -0.92387953251f, -0.70710678119f, -0.38268343236f };
#pragma unroll
    for (int s = 1; s <= 4; ++s) {
        const int len = 1 << s;
        const int half = len >> 1;
        const int step = 16 >> s;
#pragma unroll
        for (int i = 0; i < 16; i += len) {
#pragma unroll
            for (int j = 0; j < half; ++j) {
                const float wr = C[j * step];
                const float wi = S16[j * step];
                const int p = i + j;
                const int q = i + j + half;
                const float vr = re[q] * wr - im[q] * wi;
                const float vi = re[q] * wi + im[q] * wr;
                const float ur = re[p], ui = im[p];
                re[p] = ur + vr; im[p] = ui + vi;
                re[q] = ur - vr; im[q] = ui - vi;
            }
        }
    }
}

__global__ __launch_bounds__(256) void fft256_kernel(const float* __restrict__ x,
                                                     float* __restrict__ out) {
    __shared__ float tile[NB * TS];

    const int tid = threadIdx.x;
    const int sub = tid >> 4;
    const int t   = tid & 15;
    float* L = tile + sub * TS;  // wave-private 16x17 tile, reused every iter

    for (int it = 0; it < BPT; ++it) {
        const long b = (long)blockIdx.x * (NB * BPT) + it * NB + sub;

        const float* xr = x + b * 512;   // x[b, 0, :]
        const float* xi = xr + 256;      // x[b, 1, :]

        float re[16], im[16];

        // Plain loads: input stays L3-resident across timed replays.
#pragma unroll
        for (int i = 0; i < 16; ++i) re[i] = xr[t + 16 * i];
#pragma unroll
        for (int i = 0; i < 16; ++i) im[i] = xi[t + 16 * i];

        fft16(re, im);  // Y[t, k2] over n2

        // Twiddle W_256^{t*k}. Imag rows to LDS now; real kept in re[].
#pragma unroll
        for (int k = 0; k < 16; ++k) {
            float sv, cv;
            __sincosf(-6.283185307179586f * (float)(t * k) * (1.0f / 256.0f), &sv, &cv);
            const float tr = re[k] * cv - im[k] * sv;
            const float ti = re[k] * sv + im[k] * cv;
            L[17 * t + k] = ti;
            re[k] = tr;
        }
        wave_fence();

        // Transpose pass 1: imag columns out.
#pragma unroll
        for (int n = 0; n < 16; ++n) im[n] = L[17 * n + t];
        wave_fence();

        // Transpose pass 2: real rows in, columns out.
#pragma unroll
        for (int k = 0; k < 16; ++k) L[17 * t + k] = re[k];
        wave_fence();
#pragma unroll
        for (int n = 0; n < 16; ++n) re[n] = L[17 * n + t];

        fft16(re, im);  // X[t + 16*k1] over k1

        // NT stores: write-once output, evict-first.
        float* outr = out + b * 512;
        float* outi = outr + 256;
#pragma unroll
        for (int k = 0; k < 16; ++k) __builtin_nontemporal_store(re[k], outr + t + 16 * k);
#pragma unroll
        for (int k = 0; k < 16; ++k) __builtin_nontemporal_store(im[k], outi + t + 16 * k);

        // Pin iteration boundary: no cross-iteration scheduling (register
        // growth) and the next twiddle-write can't pass this iter's reads.
        wave_fence();
        __builtin_amdgcn_sched_barrier(0);
    }
}

extern "C" void kernel_launch(void* const* d_in, const int* in_sizes, int n_in,
                              void* d_out, int out_size, void* d_ws, size_t ws_size,
                              hipStream_t stream) {
    (void)d_ws; (void)ws_size; (void)n_in; (void)out_size;
    const float* x = (const float*)d_in[0];
    float* out = (float*)d_out;
    const int batches = in_sizes[0] / 512;        // 131072
    const int grid = batches / (NB * BPT);        // 2048 blocks
    fft256_kernel<<<grid, 256, 0, stream>>>(x, out);
}

// Round 15
// 95.777 us; speedup vs baseline: 2.9037x; 1.0409x over previous
//
#include <hip/hip_runtime.h>
#include <math.h>

// 256-point FFT = 16x16 four-step Cooley-Tukey, one batch per 16 lanes,
// TWO batches per thread (compiler serializes them -- measured best
// config at 95.7us, round 11). Final state after 7 structural
// experiments (rounds 3-14): this is the practical floor.
//
// Keep decisions and their evidence:
// - PLAIN loads: input (256 MiB = L3 size) stays ~50% L3-resident across
//   timed replays; nt loads defeated residency (FETCH 230->131MB, r8).
// - NT stores: output is write-once; WRITE_SIZE clean at ~273MB (r8/r11).
// - 16x17-padded wave-private LDS tile, imag-then-real reuse: zero bank
//   conflicts; wave_fence (not __syncthreads) suffices -- per-wave DS
//   ops are in-order and the tile is wave-private.
// - 2*NB tiles = 34.8 KB LDS/block: steers the backend occupancy target
//   to 4 waves/EU -> 128-VGPR budget -> no spills (r9/r10: 17.4KB made
//   it target 8 waves/EU and spill; spill signature = WRITE +70MB).
// - No reg-prefetch beyond this: allocator refuses >64 live VGPRs
//   (r9-11); no DMA double-buffer: bank conflicts + 2-blocks/CU lose
//   more than MLP gains (r12); no shfl transpose: DS-pipe ops + scratch
//   demotion, 70M conflicts (r13); no serial multi-batch: neutral (r14).

#define NB 16   // batch-pairs per 256-thread block (32 batches/block)
#define TS 272  // 16*17 floats per-batch tile

__device__ __forceinline__ void wave_fence() {
    __builtin_amdgcn_wave_barrier();
}

__device__ __forceinline__ void fft16(float re[16], float im[16]) {
    // 4-bit bit-reversal permutation (swap i < rev(i))
    {
        float tr, ti;
#define SWP(a, b) tr = re[a]; re[a] = re[b]; re[b] = tr; ti = im[a]; im[a] = im[b]; im[b] = ti;
        SWP(1, 8) SWP(2, 4) SWP(3, 12) SWP(5, 10) SWP(7, 14) SWP(11, 13)
#undef SWP
    }
    const float C[8] = { 1.0f,  0.92387953251f,  0.70710678119f,  0.38268343236f,
                         0.0f, -0.38268343236f, -0.70710678119f, -0.92387953251f };
    const float S16[8] = { 0.0f, -0.38268343236f, -0.70710678119f, -0.92387953251f,
                          -1.0f, -0.92387953251f, -0.70710678119f, -0.38268343236f };
#pragma unroll
    for (int s = 1; s <= 4; ++s) {
        const int len = 1 << s;
        const int half = len >> 1;
        const int step = 16 >> s;
#pragma unroll
        for (int i = 0; i < 16; i += len) {
#pragma unroll
            for (int j = 0; j < half; ++j) {
                const float wr = C[j * step];
                const float wi = S16[j * step];
                const int p = i + j;
                const int q = i + j + half;
                const float vr = re[q] * wr - im[q] * wi;
                const float vi = re[q] * wi + im[q] * wr;
                const float ur = re[p], ui = im[p];
                re[p] = ur + vr; im[p] = ui + vi;
                re[q] = ur - vr; im[q] = ui - vi;
            }
        }
    }
}

// Twiddle + LDS transpose + second FFT + nt store for one batch.
__device__ __forceinline__ void finish_batch(float re[16], float im[16],
                                             float* L, int t,
                                             float* outr, float* outi) {
#pragma unroll
    for (int k = 0; k < 16; ++k) {
        float sv, cv;
        __sincosf(-6.283185307179586f * (float)(t * k) * (1.0f / 256.0f), &sv, &cv);
        const float tr = re[k] * cv - im[k] * sv;
        const float ti = re[k] * sv + im[k] * cv;
        L[17 * t + k] = ti;   // imag rows to LDS; real kept in re[]
        re[k] = tr;
    }
    wave_fence();
#pragma unroll
    for (int n = 0; n < 16; ++n) im[n] = L[17 * n + t];   // imag columns out
    wave_fence();
#pragma unroll
    for (int k = 0; k < 16; ++k) L[17 * t + k] = re[k];   // real rows in
    wave_fence();
#pragma unroll
    for (int n = 0; n < 16; ++n) re[n] = L[17 * n + t];   // real columns out
    wave_fence();

    fft16(re, im);  // X[t + 16*k1] over k1

#pragma unroll
    for (int k = 0; k < 16; ++k) __builtin_nontemporal_store(re[k], outr + t + 16 * k);
#pragma unroll
    for (int k = 0; k < 16; ++k) __builtin_nontemporal_store(im[k], outi + t + 16 * k);
}

__global__ __launch_bounds__(256, 4) void fft256_kernel(const float* __restrict__ x,
                                                        float* __restrict__ out) {
    // 2*NB tiles: batch A and batch B each get their own. 34816 B/block
    // -> backend occupancy target 4 waves/EU -> 128-VGPR budget.
    __shared__ float tile[2 * NB * TS];

    const int tid = threadIdx.x;
    const int sub = tid >> 4;
    const int t   = tid & 15;
    const long b0 = (long)blockIdx.x * (2 * NB) + sub;  // batch A
    const long b1 = b0 + NB;                            // batch B

    const float* xrA = x + b0 * 512;
    const float* xiA = xrA + 256;
    const float* xrB = x + b1 * 512;
    const float* xiB = xrB + 256;

    float reA[16], imA[16], reB[16], imB[16];

    // Issue all loads up front; the compiler serializes what it must,
    // keeps what it can in flight.
#pragma unroll
    for (int i = 0; i < 16; ++i) reA[i] = xrA[t + 16 * i];
#pragma unroll
    for (int i = 0; i < 16; ++i) imA[i] = xiA[t + 16 * i];
#pragma unroll
    for (int i = 0; i < 16; ++i) reB[i] = xrB[t + 16 * i];
#pragma unroll
    for (int i = 0; i < 16; ++i) imB[i] = xiB[t + 16 * i];

    float* LA = tile + sub * TS;             // batch A tile
    float* LB = tile + (NB + sub) * TS;      // batch B tile

    // ---- Batch A
    fft16(reA, imA);
    finish_batch(reA, imA, LA, t, out + b0 * 512, out + b0 * 512 + 256);

    // ---- Batch B
    fft16(reB, imB);
    finish_batch(reB, imB, LB, t, out + b1 * 512, out + b1 * 512 + 256);
}

extern "C" void kernel_launch(void* const* d_in, const int* in_sizes, int n_in,
                              void* d_out, int out_size, void* d_ws, size_t ws_size,
                              hipStream_t stream) {
    (void)d_ws; (void)ws_size; (void)n_in; (void)out_size;
    const float* x = (const float*)d_in[0];
    float* out = (float*)d_out;
    const int batches = in_sizes[0] / 512;        // 131072
    const int grid = batches / (2 * NB);          // 4096 blocks
    fft256_kernel<<<grid, 256, 0, stream>>>(x, out);
}